// Round 1
// baseline (1870.840 us; speedup 1.0000x reference)
//
#include <hip/hip_runtime.h>

#define NNODES 100000
#define NEDGES 3200000
#define NFEATS 128
#define HID 64
#define NGRAPHS 64

// ---------- CSR build ----------

__global__ __launch_bounds__(256) void k_init(int* cnt_i, float* pooled, float* gcnt) {
    int i = blockIdx.x * 256 + threadIdx.x;
    if (i < NNODES) cnt_i[i] = 0;
    if (i < NGRAPHS * HID) pooled[i] = 0.f;
    if (i < NGRAPHS) gcnt[i] = 0.f;
}

__global__ __launch_bounds__(256) void k_count(const int* __restrict__ dst, int* __restrict__ cnt) {
    int e = blockIdx.x * 256 + threadIdx.x;
    if (e < NEDGES) atomicAdd(&cnt[dst[e]], 1);
}

// exclusive scan of cnt -> rowptr. 256 threads x 16 items = 4096/block.
__global__ __launch_bounds__(256) void k_scan1(const int* __restrict__ cnt, int* __restrict__ rowptr,
                                               int* __restrict__ bsums) {
    __shared__ int sh[256];
    int tid = threadIdx.x;
    int base = blockIdx.x * 4096 + tid * 16;
    int v[16];
    int s = 0;
#pragma unroll
    for (int p = 0; p < 16; p++) {
        int idx = base + p;
        int c = (idx < NNODES) ? cnt[idx] : 0;
        v[p] = s;
        s += c;
    }
    sh[tid] = s;
    __syncthreads();
    for (int off = 1; off < 256; off <<= 1) {
        int t = (tid >= off) ? sh[tid - off] : 0;
        __syncthreads();
        sh[tid] += t;
        __syncthreads();
    }
    int excl = tid ? sh[tid - 1] : 0;
#pragma unroll
    for (int p = 0; p < 16; p++) {
        int idx = base + p;
        if (idx < NNODES) rowptr[idx] = excl + v[p];
    }
    if (tid == 255) bsums[blockIdx.x] = sh[255];
}

__global__ void k_scan2(int* bsums, int nb) {
    int run = 0;
    for (int b = 0; b < nb; b++) { int t = bsums[b]; bsums[b] = run; run += t; }
}

__global__ __launch_bounds__(256) void k_scan3(const int* __restrict__ cnt, int* __restrict__ rowptr,
                                               int* __restrict__ cursor, float* __restrict__ dinv,
                                               const int* __restrict__ bsums) {
    int i = blockIdx.x * 256 + threadIdx.x;
    if (i >= NNODES) return;
    int r = rowptr[i] + bsums[i >> 12];
    rowptr[i] = r;
    cursor[i] = r;
    dinv[i] = rsqrtf((float)(cnt[i] + 1));   // +1 = self loop; always > 0
}

// pack (src, dinv[s]*dinv[d]) into one 8B record at CSR position
__global__ __launch_bounds__(256) void k_fill(const int* __restrict__ src, const int* __restrict__ dst,
                                              int* __restrict__ cursor, const float* __restrict__ dinv,
                                              float2* __restrict__ colw) {
    int e = blockIdx.x * 256 + threadIdx.x;
    if (e >= NEDGES) return;
    int s = src[e], d = dst[e];
    int p = atomicAdd(&cursor[d], 1);
    colw[p] = make_float2(__int_as_float(s), dinv[s] * dinv[d]);
}

// ---------- per-layer kernels ----------

// t_out = (RELU? relu(in) : in) @ W ; agg = bias + t_out * dinv^2  (self-loop + bias init)
// one wave per node, lane = output feature. Safe when in == agg: every store
// depends (via shfl dataflow) on all of this wave's input loads.
template <int K, bool RELU>
__global__ __launch_bounds__(256) void k_mm(const float* __restrict__ in, const float* __restrict__ W,
                                            const float* __restrict__ bias, const float* __restrict__ dinv,
                                            float* __restrict__ t_out, float* agg) {
    __shared__ float Wl[K * 64];
    int tid = threadIdx.x;
    for (int p = tid; p < K * 64; p += 256) Wl[p] = W[p];
    __syncthreads();
    int lane = tid & 63, wid = tid >> 6;
    int node = blockIdx.x * 4 + wid;
    if (node >= NNODES) return;
    float xr[K / 64];
#pragma unroll
    for (int p = 0; p < K / 64; p++) {
        float u = in[node * K + p * 64 + lane];
        if (RELU) u = fmaxf(u, 0.f);
        xr[p] = u;
    }
    float acc = 0.f;
#pragma unroll
    for (int p = 0; p < K / 64; p++) {
#pragma unroll
        for (int kk = 0; kk < 64; kk++) {
            acc = fmaf(__shfl(xr[p], kk), Wl[(p * 64 + kk) * 64 + lane], acc);
        }
    }
    float dv = dinv[node];
    t_out[node * 64 + lane] = acc;
    agg[node * 64 + lane] = bias[lane] + acc * dv * dv;
}

// agg[i] += sum_e w_e * t[src_e]   — one wave per node, no atomics
__global__ __launch_bounds__(256) void k_agg(const float* __restrict__ t, const int* __restrict__ rowptr,
                                             const int* __restrict__ cnt, const float2* __restrict__ colw,
                                             float* __restrict__ agg) {
    int w = (blockIdx.x * 256 + threadIdx.x) >> 6;
    int lane = threadIdx.x & 63;
    if (w >= NNODES) return;
    int start = rowptr[w];
    int n = cnt[w];
    float acc = 0.f;
    int e = 0;
    for (; e + 4 <= n; e += 4) {
        float2 p0 = colw[start + e + 0];
        float2 p1 = colw[start + e + 1];
        float2 p2 = colw[start + e + 2];
        float2 p3 = colw[start + e + 3];
        float v0 = t[__float_as_int(p0.x) * 64 + lane];
        float v1 = t[__float_as_int(p1.x) * 64 + lane];
        float v2 = t[__float_as_int(p2.x) * 64 + lane];
        float v3 = t[__float_as_int(p3.x) * 64 + lane];
        acc += p0.y * v0 + p1.y * v1 + p2.y * v2 + p3.y * v3;
    }
    for (; e < n; e++) {
        float2 p = colw[start + e];
        acc += p.y * t[__float_as_int(p.x) * 64 + lane];
    }
    agg[w * 64 + lane] += acc;
}

// ---------- pooling + head ----------

__global__ __launch_bounds__(256) void k_pool(const float* __restrict__ h, const int* __restrict__ batch,
                                              float* pooled, float* gcnt) {
    int i = (blockIdx.x * 256 + threadIdx.x) >> 6;
    int lane = threadIdx.x & 63;
    if (i >= NNODES) return;
    int g = batch[i];
    float v = fmaxf(h[i * 64 + lane], 0.f);   // relu of layer-3 output
    atomicAdd(&pooled[g * 64 + lane], v);
    if (lane == 0) atomicAdd(&gcnt[g], 1.f);
}

__global__ __launch_bounds__(256) void k_final(const float* __restrict__ pooled, const float* __restrict__ gcnt,
                                               const float* __restrict__ Wl, const float* __restrict__ bl,
                                               float* __restrict__ out) {
    int g = (blockIdx.x * 256 + threadIdx.x) >> 6;
    int lane = threadIdx.x & 63;
    if (g >= NGRAPHS) return;
    float c = fmaxf(gcnt[g], 1.f);
    float v = pooled[g * 64 + lane] / c * Wl[lane];
#pragma unroll
    for (int off = 32; off; off >>= 1) v += __shfl_down(v, off);
    if (lane == 0) out[g] = v + bl[0];
}

// ---------- launch ----------

extern "C" void kernel_launch(void* const* d_in, const int* in_sizes, int n_in,
                              void* d_out, int out_size, void* d_ws, size_t ws_size,
                              hipStream_t stream) {
    const float* x  = (const float*)d_in[0];
    const int* ei   = (const int*)d_in[1];
    const int* batch = (const int*)d_in[2];
    const float* W1 = (const float*)d_in[3];
    const float* b1 = (const float*)d_in[4];
    const float* W2 = (const float*)d_in[5];
    const float* b2 = (const float*)d_in[6];
    const float* W3 = (const float*)d_in[7];
    const float* b3 = (const float*)d_in[8];
    const float* Wl = (const float*)d_in[9];
    const float* bl = (const float*)d_in[10];
    const int* src = ei;
    const int* dst = ei + NEDGES;

    char* ws = (char*)d_ws;
    size_t off = 0;
    auto alloc = [&](size_t bytes) { void* p = ws + off; off += (bytes + 255) & ~size_t(255); return p; };
    float*  A      = (float*)alloc((size_t)NNODES * 64 * 4);
    float*  B      = (float*)alloc((size_t)NNODES * 64 * 4);
    float2* colw   = (float2*)alloc((size_t)NEDGES * 8);
    float*  dinv   = (float*)alloc((size_t)NNODES * 4);
    int*    cnti   = (int*)alloc((size_t)NNODES * 4);
    int*    rowptr = (int*)alloc((size_t)NNODES * 4);
    int*    cursor = (int*)alloc((size_t)NNODES * 4);
    int*    bsums  = (int*)alloc(32 * 4);
    float*  pooled = (float*)alloc(NGRAPHS * 64 * 4);
    float*  gcnt   = (float*)alloc(NGRAPHS * 4);
    float*  out    = (float*)d_out;

    const int NB_N  = (NNODES + 255) / 256;
    const int NB_E  = (NEDGES + 255) / 256;
    const int NB_SC = (NNODES + 4095) / 4096;
    const int NB_MM = (NNODES + 3) / 4;
    const int NB_W  = ((size_t)NNODES * 64 + 255) / 256;

    k_init<<<NB_N, 256, 0, stream>>>(cnti, pooled, gcnt);
    k_count<<<NB_E, 256, 0, stream>>>(dst, cnti);
    k_scan1<<<NB_SC, 256, 0, stream>>>(cnti, rowptr, bsums);
    k_scan2<<<1, 1, 0, stream>>>(bsums, NB_SC);
    k_scan3<<<NB_N, 256, 0, stream>>>(cnti, rowptr, cursor, dinv, bsums);
    k_fill<<<NB_E, 256, 0, stream>>>(src, dst, cursor, dinv, colw);

    // layer 1: x[N,128] -> A (transform), B (agg init); then aggregate into B
    k_mm<128, false><<<NB_MM, 256, 0, stream>>>(x, W1, b1, dinv, A, B);
    k_agg<<<NB_W, 256, 0, stream>>>(A, rowptr, cnti, colw, B);
    // layer 2 (relu on read)
    k_mm<64, true><<<NB_MM, 256, 0, stream>>>(B, W2, b2, dinv, A, B);
    k_agg<<<NB_W, 256, 0, stream>>>(A, rowptr, cnti, colw, B);
    // layer 3
    k_mm<64, true><<<NB_MM, 256, 0, stream>>>(B, W3, b3, dinv, A, B);
    k_agg<<<NB_W, 256, 0, stream>>>(A, rowptr, cnti, colw, B);

    k_pool<<<NB_W, 256, 0, stream>>>(B, batch, pooled, gcnt);
    k_final<<<(NGRAPHS * 64 + 255) / 256, 256, 0, stream>>>(pooled, gcnt, Wl, bl, out);
}

// Round 2
// 1144.568 us; speedup vs baseline: 1.6345x; 1.6345x over previous
//
#include <hip/hip_runtime.h>

#define NNODES 100000
#define NEDGES 3200000
#define NFEATS 128
#define HID 64
#define NGRAPHS 64

// ---------- CSR build ----------

__global__ __launch_bounds__(256) void k_init(int* cnt_i, float* pooled, float* gcnt) {
    int i = blockIdx.x * 256 + threadIdx.x;
    if (i < NNODES) cnt_i[i] = 0;
    if (i < NGRAPHS * HID) pooled[i] = 0.f;
    if (i < NGRAPHS) gcnt[i] = 0.f;
}

__global__ __launch_bounds__(256) void k_count(const int* __restrict__ dst, int* __restrict__ cnt) {
    int e = blockIdx.x * 256 + threadIdx.x;
    if (e < NEDGES) atomicAdd(&cnt[dst[e]], 1);
}

// exclusive scan of cnt -> rowptr. 256 threads x 16 items = 4096/block.
__global__ __launch_bounds__(256) void k_scan1(const int* __restrict__ cnt, int* __restrict__ rowptr,
                                               int* __restrict__ bsums) {
    __shared__ int sh[256];
    int tid = threadIdx.x;
    int base = blockIdx.x * 4096 + tid * 16;
    int v[16];
    int s = 0;
#pragma unroll
    for (int p = 0; p < 16; p++) {
        int idx = base + p;
        int c = (idx < NNODES) ? cnt[idx] : 0;
        v[p] = s;
        s += c;
    }
    sh[tid] = s;
    __syncthreads();
    for (int off = 1; off < 256; off <<= 1) {
        int t = (tid >= off) ? sh[tid - off] : 0;
        __syncthreads();
        sh[tid] += t;
        __syncthreads();
    }
    int excl = tid ? sh[tid - 1] : 0;
#pragma unroll
    for (int p = 0; p < 16; p++) {
        int idx = base + p;
        if (idx < NNODES) rowptr[idx] = excl + v[p];
    }
    if (tid == 255) bsums[blockIdx.x] = sh[255];
}

__global__ void k_scan2(int* bsums, int nb) {
    int run = 0;
    for (int b = 0; b < nb; b++) { int t = bsums[b]; bsums[b] = run; run += t; }
}

__global__ __launch_bounds__(256) void k_scan3(const int* __restrict__ cnt, int* __restrict__ rowptr,
                                               int* __restrict__ cursor, float* __restrict__ dinv,
                                               const int* __restrict__ bsums) {
    int i = blockIdx.x * 256 + threadIdx.x;
    if (i >= NNODES) return;
    int r = rowptr[i] + bsums[i >> 12];
    rowptr[i] = r;
    cursor[i] = r;
    dinv[i] = rsqrtf((float)(cnt[i] + 1));   // +1 = self loop; always > 0
}

// pack (src, dinv[s]*dinv[d]) into one 8B record at CSR position
__global__ __launch_bounds__(256) void k_fill(const int* __restrict__ src, const int* __restrict__ dst,
                                              int* __restrict__ cursor, const float* __restrict__ dinv,
                                              float2* __restrict__ colw) {
    int e = blockIdx.x * 256 + threadIdx.x;
    if (e >= NEDGES) return;
    int s = src[e], d = dst[e];
    int p = atomicAdd(&cursor[d], 1);
    colw[p] = make_float2(__int_as_float(s), dinv[s] * dinv[d]);
}

// ---------- per-layer kernels ----------

// t_out = (RELU? relu(in) : in) @ W ; agg = bias + t_out * dinv^2  (self-loop + bias init)
// one wave per node, lane = output feature. Safe when in == agg: every store
// depends (via shfl dataflow) on all of this wave's input loads.
template <int K, bool RELU>
__global__ __launch_bounds__(256) void k_mm(const float* __restrict__ in, const float* __restrict__ W,
                                            const float* __restrict__ bias, const float* __restrict__ dinv,
                                            float* __restrict__ t_out, float* agg) {
    __shared__ float Wl[K * 64];
    int tid = threadIdx.x;
    for (int p = tid; p < K * 64; p += 256) Wl[p] = W[p];
    __syncthreads();
    int lane = tid & 63, wid = tid >> 6;
    int node = blockIdx.x * 4 + wid;
    if (node >= NNODES) return;
    float xr[K / 64];
#pragma unroll
    for (int p = 0; p < K / 64; p++) {
        float u = in[node * K + p * 64 + lane];
        if (RELU) u = fmaxf(u, 0.f);
        xr[p] = u;
    }
    float acc = 0.f;
#pragma unroll
    for (int p = 0; p < K / 64; p++) {
#pragma unroll
        for (int kk = 0; kk < 64; kk++) {
            acc = fmaf(__shfl(xr[p], kk), Wl[(p * 64 + kk) * 64 + lane], acc);
        }
    }
    float dv = dinv[node];
    t_out[node * 64 + lane] = acc;
    agg[node * 64 + lane] = bias[lane] + acc * dv * dv;
}

// agg[i] += sum_e w_e * t[src_e]   — one wave per node, no atomics
__global__ __launch_bounds__(256) void k_agg(const float* __restrict__ t, const int* __restrict__ rowptr,
                                             const int* __restrict__ cnt, const float2* __restrict__ colw,
                                             float* __restrict__ agg) {
    int w = (blockIdx.x * 256 + threadIdx.x) >> 6;
    int lane = threadIdx.x & 63;
    if (w >= NNODES) return;
    int start = rowptr[w];
    int n = cnt[w];
    float acc = 0.f;
    int e = 0;
    for (; e + 4 <= n; e += 4) {
        float2 p0 = colw[start + e + 0];
        float2 p1 = colw[start + e + 1];
        float2 p2 = colw[start + e + 2];
        float2 p3 = colw[start + e + 3];
        float v0 = t[__float_as_int(p0.x) * 64 + lane];
        float v1 = t[__float_as_int(p1.x) * 64 + lane];
        float v2 = t[__float_as_int(p2.x) * 64 + lane];
        float v3 = t[__float_as_int(p3.x) * 64 + lane];
        acc += p0.y * v0 + p1.y * v1 + p2.y * v2 + p3.y * v3;
    }
    for (; e < n; e++) {
        float2 p = colw[start + e];
        acc += p.y * t[__float_as_int(p.x) * 64 + lane];
    }
    agg[w * 64 + lane] += acc;
}

// ---------- pooling + head ----------

// batch is SORTED: segmented reduction. One wave per POOL_CHUNK consecutive
// nodes (lane = feature); flush one atomicAdd per segment-within-chunk.
#define POOL_CHUNK 256
__global__ __launch_bounds__(256) void k_pool(const float* __restrict__ h, const int* __restrict__ batch,
                                              float* pooled, float* gcnt) {
    int w = (blockIdx.x * 256 + threadIdx.x) >> 6;
    int lane = threadIdx.x & 63;
    int start = w * POOL_CHUNK;
    if (start >= NNODES) return;
    int end = min(start + POOL_CHUNK, NNODES);
    int g = batch[start];
    float acc = 0.f;
    int cn = 0;
    for (int i = start; i < end; i++) {
        int gi = batch[i];
        if (gi != g) {
            atomicAdd(&pooled[g * 64 + lane], acc);
            if (lane == 0) atomicAdd(&gcnt[g], (float)cn);
            g = gi; acc = 0.f; cn = 0;
        }
        acc += fmaxf(h[i * 64 + lane], 0.f);   // relu of layer-3 output
        cn++;
    }
    atomicAdd(&pooled[g * 64 + lane], acc);
    if (lane == 0) atomicAdd(&gcnt[g], (float)cn);
}

__global__ __launch_bounds__(256) void k_final(const float* __restrict__ pooled, const float* __restrict__ gcnt,
                                               const float* __restrict__ Wl, const float* __restrict__ bl,
                                               float* __restrict__ out) {
    int g = (blockIdx.x * 256 + threadIdx.x) >> 6;
    int lane = threadIdx.x & 63;
    if (g >= NGRAPHS) return;
    float c = fmaxf(gcnt[g], 1.f);
    float v = pooled[g * 64 + lane] / c * Wl[lane];
#pragma unroll
    for (int off = 32; off; off >>= 1) v += __shfl_down(v, off);
    if (lane == 0) out[g] = v + bl[0];
}

// ---------- launch ----------

extern "C" void kernel_launch(void* const* d_in, const int* in_sizes, int n_in,
                              void* d_out, int out_size, void* d_ws, size_t ws_size,
                              hipStream_t stream) {
    const float* x  = (const float*)d_in[0];
    const int* ei   = (const int*)d_in[1];
    const int* batch = (const int*)d_in[2];
    const float* W1 = (const float*)d_in[3];
    const float* b1 = (const float*)d_in[4];
    const float* W2 = (const float*)d_in[5];
    const float* b2 = (const float*)d_in[6];
    const float* W3 = (const float*)d_in[7];
    const float* b3 = (const float*)d_in[8];
    const float* Wl = (const float*)d_in[9];
    const float* bl = (const float*)d_in[10];
    const int* src = ei;
    const int* dst = ei + NEDGES;

    char* ws = (char*)d_ws;
    size_t off = 0;
    auto alloc = [&](size_t bytes) { void* p = ws + off; off += (bytes + 255) & ~size_t(255); return p; };
    float*  A      = (float*)alloc((size_t)NNODES * 64 * 4);
    float*  B      = (float*)alloc((size_t)NNODES * 64 * 4);
    float2* colw   = (float2*)alloc((size_t)NEDGES * 8);
    float*  dinv   = (float*)alloc((size_t)NNODES * 4);
    int*    cnti   = (int*)alloc((size_t)NNODES * 4);
    int*    rowptr = (int*)alloc((size_t)NNODES * 4);
    int*    cursor = (int*)alloc((size_t)NNODES * 4);
    int*    bsums  = (int*)alloc(32 * 4);
    float*  pooled = (float*)alloc(NGRAPHS * 64 * 4);
    float*  gcnt   = (float*)alloc(NGRAPHS * 4);
    float*  out    = (float*)d_out;

    const int NB_N  = (NNODES + 255) / 256;
    const int NB_E  = (NEDGES + 255) / 256;
    const int NB_SC = (NNODES + 4095) / 4096;
    const int NB_MM = (NNODES + 3) / 4;
    const int NB_W  = ((size_t)NNODES * 64 + 255) / 256;
    const int NB_PL = ((NNODES + POOL_CHUNK - 1) / POOL_CHUNK + 3) / 4;

    k_init<<<NB_N, 256, 0, stream>>>(cnti, pooled, gcnt);
    k_count<<<NB_E, 256, 0, stream>>>(dst, cnti);
    k_scan1<<<NB_SC, 256, 0, stream>>>(cnti, rowptr, bsums);
    k_scan2<<<1, 1, 0, stream>>>(bsums, NB_SC);
    k_scan3<<<NB_N, 256, 0, stream>>>(cnti, rowptr, cursor, dinv, bsums);
    k_fill<<<NB_E, 256, 0, stream>>>(src, dst, cursor, dinv, colw);

    // layer 1: x[N,128] -> A (transform), B (agg init); then aggregate into B
    k_mm<128, false><<<NB_MM, 256, 0, stream>>>(x, W1, b1, dinv, A, B);
    k_agg<<<NB_W, 256, 0, stream>>>(A, rowptr, cnti, colw, B);
    // layer 2 (relu on read)
    k_mm<64, true><<<NB_MM, 256, 0, stream>>>(B, W2, b2, dinv, A, B);
    k_agg<<<NB_W, 256, 0, stream>>>(A, rowptr, cnti, colw, B);
    // layer 3
    k_mm<64, true><<<NB_MM, 256, 0, stream>>>(B, W3, b3, dinv, A, B);
    k_agg<<<NB_W, 256, 0, stream>>>(A, rowptr, cnti, colw, B);

    k_pool<<<NB_PL, 256, 0, stream>>>(B, batch, pooled, gcnt);
    k_final<<<(NGRAPHS * 64 + 255) / 256, 256, 0, stream>>>(pooled, gcnt, Wl, bl, out);
}

// Round 3
// 911.214 us; speedup vs baseline: 2.0531x; 1.2561x over previous
//
#include <hip/hip_runtime.h>

#define NNODES 100000
#define NEDGES 3200000
#define NFEATS 128
#define HID 64
#define NGRAPHS 64

// ---------- CSR build ----------

__global__ __launch_bounds__(256) void k_init(int* cnt_i, float* pooled, float* gcnt) {
    int i = blockIdx.x * 256 + threadIdx.x;
    if (i < NNODES) cnt_i[i] = 0;
    if (i < NGRAPHS * HID) pooled[i] = 0.f;
    if (i < NGRAPHS) gcnt[i] = 0.f;
}

__global__ __launch_bounds__(256) void k_count(const int* __restrict__ dst, int* __restrict__ cnt) {
    int e = blockIdx.x * 256 + threadIdx.x;
    if (e < NEDGES) atomicAdd(&cnt[dst[e]], 1);
}

// exclusive scan of cnt -> rowptr. 256 threads x 16 items = 4096/block.
__global__ __launch_bounds__(256) void k_scan1(const int* __restrict__ cnt, int* __restrict__ rowptr,
                                               int* __restrict__ bsums) {
    __shared__ int sh[256];
    int tid = threadIdx.x;
    int base = blockIdx.x * 4096 + tid * 16;
    int v[16];
    int s = 0;
#pragma unroll
    for (int p = 0; p < 16; p++) {
        int idx = base + p;
        int c = (idx < NNODES) ? cnt[idx] : 0;
        v[p] = s;
        s += c;
    }
    sh[tid] = s;
    __syncthreads();
    for (int off = 1; off < 256; off <<= 1) {
        int t = (tid >= off) ? sh[tid - off] : 0;
        __syncthreads();
        sh[tid] += t;
        __syncthreads();
    }
    int excl = tid ? sh[tid - 1] : 0;
#pragma unroll
    for (int p = 0; p < 16; p++) {
        int idx = base + p;
        if (idx < NNODES) rowptr[idx] = excl + v[p];
    }
    if (tid == 255) bsums[blockIdx.x] = sh[255];
}

__global__ void k_scan2(int* bsums, int nb) {
    int run = 0;
    for (int b = 0; b < nb; b++) { int t = bsums[b]; bsums[b] = run; run += t; }
}

__global__ __launch_bounds__(256) void k_scan3(const int* __restrict__ cnt, int* __restrict__ rowptr,
                                               int* __restrict__ cursor, float* __restrict__ dinv,
                                               const int* __restrict__ bsums) {
    int i = blockIdx.x * 256 + threadIdx.x;
    if (i >= NNODES) return;
    int r = rowptr[i] + bsums[i >> 12];
    rowptr[i] = r;
    cursor[i] = r;
    dinv[i] = rsqrtf((float)(cnt[i] + 1));   // +1 = self loop; always > 0
}

// pack (src, dinv[s]*dinv[d]) into one 8B record at CSR position
__global__ __launch_bounds__(256) void k_fill(const int* __restrict__ src, const int* __restrict__ dst,
                                              int* __restrict__ cursor, const float* __restrict__ dinv,
                                              float2* __restrict__ colw) {
    int e = blockIdx.x * 256 + threadIdx.x;
    if (e >= NEDGES) return;
    int s = src[e], d = dst[e];
    int p = atomicAdd(&cursor[d], 1);
    colw[p] = make_float2(__int_as_float(s), dinv[s] * dinv[d]);
}

// ---------- transform (GEMV per node, wave-uniform W -> s_load) ----------

#define CHK 32
#define CHKP 33   // +1 pad: conflict-free stride

// block = 128 nodes x 2 col-halves (256 threads). Thread owns 32 output cols
// of one node; acc in 32 VGPRs. x staged coalesced to LDS per 32-k chunk.
// Safe when in == agg: block reads exactly the rows it writes, and every
// global read precedes the final __syncthreads().
template <int K, bool RELU>
__global__ __launch_bounds__(256) void k_mm(const float* __restrict__ in, const float* __restrict__ W,
                                            const float* __restrict__ bias, const float* __restrict__ dinv,
                                            float* __restrict__ t_out, float* __restrict__ agg) {
    __shared__ float xs[128 * CHKP];
    const int tid = threadIdx.x;
    const int lane = tid & 63;
    const int wid = tid >> 6;
    // wave-uniform column half; pin to SGPR so W loads scalarize
    const int jhalf = __builtin_amdgcn_readfirstlane(wid & 1);
    const int nloc = (wid >> 1) * 64 + lane;   // 0..127 local node
    const int node0 = blockIdx.x * 128;
    const int node = node0 + nloc;

    float acc[32];
#pragma unroll
    for (int j = 0; j < 32; j++) acc[j] = 0.f;

    const int c4 = tid & 7;     // float4 slot in row (8 per 32-float chunk)
    const int r0 = tid >> 3;    // 0..31

    for (int ko = 0; ko < K; ko += CHK) {
        __syncthreads();
#pragma unroll
        for (int s = 0; s < 4; s++) {
            int r = r0 + s * 32;
            int gn = node0 + r;
            float4 v = make_float4(0.f, 0.f, 0.f, 0.f);
            if (gn < NNODES) v = *(const float4*)&in[(size_t)gn * K + ko + c4 * 4];
            if (RELU) {
                v.x = fmaxf(v.x, 0.f); v.y = fmaxf(v.y, 0.f);
                v.z = fmaxf(v.z, 0.f); v.w = fmaxf(v.w, 0.f);
            }
            float* dp = &xs[r * CHKP + c4 * 4];
            dp[0] = v.x; dp[1] = v.y; dp[2] = v.z; dp[3] = v.w;
        }
        __syncthreads();
        for (int kk = 0; kk < CHK; kk++) {
            float xk = xs[nloc * CHKP + kk];
            const float* Wr = &W[(size_t)(ko + kk) * 64 + jhalf * 32];
#pragma unroll
            for (int j = 0; j < 32; j++) acc[j] = fmaf(xk, Wr[j], acc[j]);
        }
    }

    if (node < NNODES) {
        float dv = dinv[node];
        float dv2 = dv * dv;
        float* tp = &t_out[(size_t)node * 64 + jhalf * 32];
        float* ap = &agg[(size_t)node * 64 + jhalf * 32];
#pragma unroll
        for (int j4 = 0; j4 < 8; j4++) {
            float4 tv = make_float4(acc[j4*4], acc[j4*4+1], acc[j4*4+2], acc[j4*4+3]);
            *(float4*)&tp[j4 * 4] = tv;
            float4 av;
            av.x = bias[jhalf*32 + j4*4 + 0] + tv.x * dv2;
            av.y = bias[jhalf*32 + j4*4 + 1] + tv.y * dv2;
            av.z = bias[jhalf*32 + j4*4 + 2] + tv.z * dv2;
            av.w = bias[jhalf*32 + j4*4 + 3] + tv.w * dv2;
            *(float4*)&ap[j4 * 4] = av;
        }
    }
}

// ---------- aggregation: 4 edges in flight, float4 gathers ----------

__global__ __launch_bounds__(256) void k_agg(const float* __restrict__ t, const int* __restrict__ rowptr,
                                             const int* __restrict__ cnt, const float2* __restrict__ colw,
                                             float* __restrict__ agg) {
    int w = (blockIdx.x * 256 + threadIdx.x) >> 6;   // node
    int lane = threadIdx.x & 63;
    if (w >= NNODES) return;
    int qg = lane >> 4;      // edge-slot group 0..3
    int ql = lane & 15;      // float4 slot within the 64-float row
    int start = rowptr[w];
    int n = cnt[w];
    float4 acc = make_float4(0.f, 0.f, 0.f, 0.f);
    for (int e = qg; e < n; e += 4) {
        float2 p = colw[start + e];
        float4 v = *(const float4*)&t[(size_t)__float_as_int(p.x) * 64 + ql * 4];
        acc.x = fmaf(p.y, v.x, acc.x);
        acc.y = fmaf(p.y, v.y, acc.y);
        acc.z = fmaf(p.y, v.z, acc.z);
        acc.w = fmaf(p.y, v.w, acc.w);
    }
    // reduce the 4 edge-slot groups (lanes l, l^16, l^32, l^48)
    acc.x += __shfl_xor(acc.x, 16); acc.y += __shfl_xor(acc.y, 16);
    acc.z += __shfl_xor(acc.z, 16); acc.w += __shfl_xor(acc.w, 16);
    acc.x += __shfl_xor(acc.x, 32); acc.y += __shfl_xor(acc.y, 32);
    acc.z += __shfl_xor(acc.z, 32); acc.w += __shfl_xor(acc.w, 32);
    if (qg == 0) {
        float4* ap = (float4*)&agg[(size_t)w * 64 + ql * 4];
        float4 o = *ap;
        o.x += acc.x; o.y += acc.y; o.z += acc.z; o.w += acc.w;
        *ap = o;
    }
}

// ---------- pooling + head ----------

// batch is SORTED: segmented reduction. One wave per POOL_CHUNK consecutive
// nodes (lane = feature); flush one atomicAdd per segment-within-chunk.
#define POOL_CHUNK 256
__global__ __launch_bounds__(256) void k_pool(const float* __restrict__ h, const int* __restrict__ batch,
                                              float* pooled, float* gcnt) {
    int w = (blockIdx.x * 256 + threadIdx.x) >> 6;
    int lane = threadIdx.x & 63;
    int start = w * POOL_CHUNK;
    if (start >= NNODES) return;
    int end = min(start + POOL_CHUNK, NNODES);
    int g = batch[start];
    float acc = 0.f;
    int cn = 0;
    for (int i = start; i < end; i++) {
        int gi = batch[i];
        if (gi != g) {
            atomicAdd(&pooled[g * 64 + lane], acc);
            if (lane == 0) atomicAdd(&gcnt[g], (float)cn);
            g = gi; acc = 0.f; cn = 0;
        }
        acc += fmaxf(h[i * 64 + lane], 0.f);   // relu of layer-3 output
        cn++;
    }
    atomicAdd(&pooled[g * 64 + lane], acc);
    if (lane == 0) atomicAdd(&gcnt[g], (float)cn);
}

__global__ __launch_bounds__(256) void k_final(const float* __restrict__ pooled, const float* __restrict__ gcnt,
                                               const float* __restrict__ Wl, const float* __restrict__ bl,
                                               float* __restrict__ out) {
    int g = (blockIdx.x * 256 + threadIdx.x) >> 6;
    int lane = threadIdx.x & 63;
    if (g >= NGRAPHS) return;
    float c = fmaxf(gcnt[g], 1.f);
    float v = pooled[g * 64 + lane] / c * Wl[lane];
#pragma unroll
    for (int off = 32; off; off >>= 1) v += __shfl_down(v, off);
    if (lane == 0) out[g] = v + bl[0];
}

// ---------- launch ----------

extern "C" void kernel_launch(void* const* d_in, const int* in_sizes, int n_in,
                              void* d_out, int out_size, void* d_ws, size_t ws_size,
                              hipStream_t stream) {
    const float* x  = (const float*)d_in[0];
    const int* ei   = (const int*)d_in[1];
    const int* batch = (const int*)d_in[2];
    const float* W1 = (const float*)d_in[3];
    const float* b1 = (const float*)d_in[4];
    const float* W2 = (const float*)d_in[5];
    const float* b2 = (const float*)d_in[6];
    const float* W3 = (const float*)d_in[7];
    const float* b3 = (const float*)d_in[8];
    const float* Wl = (const float*)d_in[9];
    const float* bl = (const float*)d_in[10];
    const int* src = ei;
    const int* dst = ei + NEDGES;

    char* ws = (char*)d_ws;
    size_t off = 0;
    auto alloc = [&](size_t bytes) { void* p = ws + off; off += (bytes + 255) & ~size_t(255); return p; };
    float*  A      = (float*)alloc((size_t)NNODES * 64 * 4);
    float*  B      = (float*)alloc((size_t)NNODES * 64 * 4);
    float2* colw   = (float2*)alloc((size_t)NEDGES * 8);
    float*  dinv   = (float*)alloc((size_t)NNODES * 4);
    int*    cnti   = (int*)alloc((size_t)NNODES * 4);
    int*    rowptr = (int*)alloc((size_t)NNODES * 4);
    int*    cursor = (int*)alloc((size_t)NNODES * 4);
    int*    bsums  = (int*)alloc(32 * 4);
    float*  pooled = (float*)alloc(NGRAPHS * 64 * 4);
    float*  gcnt   = (float*)alloc(NGRAPHS * 4);
    float*  out    = (float*)d_out;

    const int NB_N  = (NNODES + 255) / 256;
    const int NB_E  = (NEDGES + 255) / 256;
    const int NB_SC = (NNODES + 4095) / 4096;
    const int NB_MM = (NNODES + 127) / 128;
    const int NB_W  = ((size_t)NNODES * 64 + 255) / 256;
    const int NB_PL = ((NNODES + POOL_CHUNK - 1) / POOL_CHUNK + 3) / 4;

    k_init<<<NB_N, 256, 0, stream>>>(cnti, pooled, gcnt);
    k_count<<<NB_E, 256, 0, stream>>>(dst, cnti);
    k_scan1<<<NB_SC, 256, 0, stream>>>(cnti, rowptr, bsums);
    k_scan2<<<1, 1, 0, stream>>>(bsums, NB_SC);
    k_scan3<<<NB_N, 256, 0, stream>>>(cnti, rowptr, cursor, dinv, bsums);
    k_fill<<<NB_E, 256, 0, stream>>>(src, dst, cursor, dinv, colw);

    // layer 1: x[N,128] -> A (transform), B (agg init); then aggregate into B
    k_mm<128, false><<<NB_MM, 256, 0, stream>>>(x, W1, b1, dinv, A, B);
    k_agg<<<NB_W, 256, 0, stream>>>(A, rowptr, cnti, colw, B);
    // layer 2 (relu on read)
    k_mm<64, true><<<NB_MM, 256, 0, stream>>>(B, W2, b2, dinv, A, B);
    k_agg<<<NB_W, 256, 0, stream>>>(A, rowptr, cnti, colw, B);
    // layer 3
    k_mm<64, true><<<NB_MM, 256, 0, stream>>>(B, W3, b3, dinv, A, B);
    k_agg<<<NB_W, 256, 0, stream>>>(A, rowptr, cnti, colw, B);

    k_pool<<<NB_PL, 256, 0, stream>>>(B, batch, pooled, gcnt);
    k_final<<<(NGRAPHS * 64 + 255) / 256, 256, 0, stream>>>(pooled, gcnt, Wl, bl, out);
}